// Round 8
// baseline (273.227 us; speedup 1.0000x reference)
//
#include <hip/hip_runtime.h>
#include <math.h>

#define IMG_H 512
#define IMG_W 512
#define NPLANES 48            // 16 * 3
#define RAD 5
#define TAPS 11
#define CHUNK 33              // multiple of 11 -> static ring phase after unroll
#define STRIP 64              // columns per wave (one autonomous wave per strip)
#define SBUF 80               // 74 used (64 + 2*RAD), padded

typedef float v2f __attribute__((ext_vector_type(2)));

// Compiler-only fence: cross-lane LDS dependence (lane i reads what lane j
// wrote) is INVISIBLE to LLVM alias analysis — R4 failed correctness exactly
// this way (reads hoisted above writes once __syncthreads was removed).
// HW needs nothing: wave has one PC and same-wave DS ops complete in order.
#define WAVE_FENCE_WAR()  __asm__ __volatile__("" ::: "memory")
#define WAVE_FENCE_RAW()  __asm__ __volatile__("s_waitcnt lgkmcnt(0)" ::: "memory")

struct GaussW { float w[TAPS]; };

// Structure notes (evidence-driven). Ledger of proven failure triggers:
//  - R2/R7: any launch-bounds reg cap below the ~104 unified (VGPR+AGPR)
//    footprint spills the 55-float ring (WRITE_SIZE 48KB -> 200+MB,
//    70 -> 219+us). Keep (256,4) = 128-reg budget.
//  - R8/R9: FULL straight-line unroll of the row loop -> scheduler pipelines
//    loads across all rows -> pressure explosion -> spill. Keep the `for kk`
//    loop + 11-row `#pragma unroll` body EXACTLY.
//  - R7/R8: raw-buffer-SRD load path: never exonerated, abandoned.
//  - R10..R13: finalize-fold arc. Fixed graph overhead ~83us regardless of
//    dispatch count (R0: 3 disp, +83; R6: 2 disp, +84) AND the folded tail
//    cost ~38us in-kernel (R13 anchor reproduced R0 exactly: 70.2us/67%
//    VALUBusy on a different container). Fold dead; keep separate finalize.
//  - R3: block-wide __syncthreads per staged row was lockstep. R5: one wave
//    per 64-col strip, no block barriers. R6: packed fp32 (v_pk_fma).
//  - R14 (this): hconv recomputed v*v and a*b for EVERY tap sliding over the
//    same pixel (33 redundant muls/row). Stage (a,b,a2,b2) as float4 + ab as
//    scalar array; hconv main = 11 b128 + 22 pk_fma; ab channel pairs
//    ADJACENT TAPS into pk_fma (5 pk + 1 fma + 1 add). ~113 -> ~88 VALU
//    insts/row. b128 reads are lane-contiguous (conflict-free canonical
//    pattern); ab pair reads stride-4B (2 lanes/bank = free).
__global__ __launch_bounds__(256, 4)
void ssim_main(const float* __restrict__ img1, const float* __restrict__ img2,
               double* __restrict__ sum_ws, GaussW gw) {
    __shared__ float4 s4[4][SBUF];     // (a, b, a2, b2) per wave
    __shared__ float  sab[4][SBUF];    // a*b per wave
    __shared__ float wsum[4];

    const int tid  = threadIdx.x;
    const int wid  = tid >> 6;         // wave id 0..3
    const int lane = tid & 63;
    const int c0   = blockIdx.x * (4 * STRIP) + wid * STRIP;  // strip base col
    const int y0   = blockIdx.y * CHUNK;
    const size_t pbase = (size_t)blockIdx.z * (IMG_H * IMG_W);
    const float* p1 = img1 + pbase;
    const float* p2 = img2 + pbase;
    float4* buf4 = s4[wid];
    float*  bufx = sab[wid];

    // register ring, 11 rows deep:
    //   rab = (conv_h(a), conv_h(b))   packed
    //   rsq = (conv_h(a^2), conv_h(b^2)) packed
    //   rx  = conv_h(a*b)              scalar
    v2f rab[TAPS], rsq[TAPS];
    float rx[TAPS];

    // prefetch registers for the next row (main col + 10-col tail)
    float pa, pb, pta, ptb;

    auto load_regs = [&](int r) {
        pa = pb = pta = ptb = 0.f;
        if (r >= 0 && r < IMG_H) {     // wave-uniform
            const float* row1 = p1 + (size_t)r * IMG_W;
            const float* row2 = p2 + (size_t)r * IMG_W;
            int col = c0 - RAD + lane;              // buf idx = lane
            if (col >= 0 && col < IMG_W) { pa = row1[col]; pb = row2[col]; }
            if (lane < 2 * RAD) {                   // buf idx = 64+lane
                int c2 = c0 + STRIP - RAD + lane;   // cols c0+59..c0+68
                if (c2 < IMG_W) { pta = row1[c2]; ptb = row2[c2]; }
            }
        }
    };

    // stage (a, b, a^2, b^2, ab): products computed ONCE per pixel here
    // instead of once per tap in hconv (11x redundancy removed).
    auto store_lds = [&]() {
        WAVE_FENCE_WAR();              // don't sink writes above prior reads
        buf4[lane] = make_float4(pa, pb, pa * pa, pb * pb);
        bufx[lane] = pa * pb;
        if (lane < 2 * RAD) {
            buf4[STRIP + lane] = make_float4(pta, ptb, pta * pta, ptb * ptb);
            bufx[STRIP + lane] = pta * ptb;
        }
        WAVE_FENCE_RAW();              // don't hoist following reads above it
    };

    // packed horizontal conv:
    //   main: per tap 1 ds_read_b128 + 2 pk_fma
    //   ab:   taps paired -> 5 pk_fma + 1 fma, then 1 horizontal add
    auto hconv = [&](int r, v2f& oab, v2f& osq, float& ox) {
        v2f aab = {0.f, 0.f}, asq = {0.f, 0.f};
        float ax = 0.f;
        if (r >= 0 && r < IMG_H) {     // wave-uniform: padded rows contribute zero
            #pragma unroll
            for (int d = 0; d < TAPS; ++d) {
                float4 v = buf4[lane + d];          // (a, b, a2, b2)
                float w = gw.w[d];
                v2f wv = {w, w};
                v2f vab = {v.x, v.y};
                v2f vsq = {v.z, v.w};
                aab = __builtin_elementwise_fma(wv, vab, aab);   // pk_fma
                asq = __builtin_elementwise_fma(wv, vsq, asq);   // pk_fma
            }
            v2f axp = {0.f, 0.f};
            #pragma unroll
            for (int d = 0; d < TAPS - 1; d += 2) {
                v2f p = *(const v2f*)&bufx[lane + d];  // (ab[d], ab[d+1])
                v2f wp = {gw.w[d], gw.w[d + 1]};
                axp = __builtin_elementwise_fma(wp, p, axp);     // pk_fma
            }
            ax = fmaf(gw.w[TAPS - 1], bufx[lane + TAPS - 1], axp.x + axp.y);
        }
        oab = aab; osq = asq; ox = ax;
    };

    // ---- prologue: h-rows 0..9 (global rows y0-5 .. y0+4) -> ring slots 0..9
    load_regs(y0 - RAD);
    #pragma unroll
    for (int k = 0; k < TAPS - 1; ++k) {
        const int r = y0 - RAD + k;
        store_lds();
        load_regs(r + 1);              // next row's loads in flight during hconv
        hconv(r, rab[k], rsq[k], rx[k]);
    }

    const float C1v = 0.0001f;  // 0.01^2
    const float C2v = 0.0009f;  // 0.03^2
    float acc = 0.f;

    // ---- main: CHUNK output rows, unrolled by 11 so ring indices are static
    for (int kk = 0; kk < CHUNK; kk += TAPS) {
        #pragma unroll
        for (int j = 0; j < TAPS; ++j) {
            const int r = y0 - RAD + (TAPS - 1) + kk + j;  // global input row
            store_lds();               // publish prefetched row r
            load_regs(r + 1);          // issue loads for row r+1 NOW
            hconv(r, rab[(j + 10) % TAPS], rsq[(j + 10) % TAPS], rx[(j + 10) % TAPS]);

            const int y = y0 + kk + j; // output row
            if (y < IMG_H) {
                // packed vertical conv: per tap 2 pk_fma + 1 fma
                v2f mu = {0.f, 0.f}, s2 = {0.f, 0.f};
                float sx = 0.f;
                #pragma unroll
                for (int t = 0; t < TAPS; ++t) {
                    const int s = (j + t) % TAPS;  // static after unroll
                    float w = gw.w[t];
                    v2f wv = {w, w};
                    mu = __builtin_elementwise_fma(wv, rab[s], mu);
                    s2 = __builtin_elementwise_fma(wv, rsq[s], s2);
                    sx = fmaf(w, rx[s], sx);
                }
                float mu1 = mu.x, mu2 = mu.y;
                float mu1sq = mu1 * mu1, mu2sq = mu2 * mu2, mu12 = mu1 * mu2;
                float sg1 = s2.x - mu1sq, sg2 = s2.y - mu2sq, sg12 = sx - mu12;
                float num = (2.f * mu12 + C1v) * (2.f * sg12 + C2v);
                float den = (mu1sq + mu2sq + C1v) * (sg1 + sg2 + C2v);
                acc += num * __builtin_amdgcn_rcpf(den);
            }
        }
    }

    // wave (64-lane) shuffle reduce -> block partials -> one atomic per block
    #pragma unroll
    for (int off = 32; off > 0; off >>= 1) acc += __shfl_down(acc, off, 64);
    if (lane == 0) wsum[wid] = acc;
    __syncthreads();                   // only block barrier in the kernel
    if (tid == 0) {
        double s = (double)wsum[0] + (double)wsum[1] + (double)wsum[2] + (double)wsum[3];
        atomicAdd(sum_ws, s);
    }
}

__global__ void ssim_finalize(const double* __restrict__ sum_ws, float* __restrict__ out) {
    out[0] = (float)(sum_ws[0] * (1.0 / (double)(16.0 * 3.0 * 512.0 * 512.0)));
}

extern "C" void kernel_launch(void* const* d_in, const int* in_sizes, int n_in,
                              void* d_out, int out_size, void* d_ws, size_t ws_size,
                              hipStream_t stream) {
    const float* img1 = (const float*)d_in[0];
    const float* img2 = (const float*)d_in[1];
    float* out = (float*)d_out;
    double* ws = (double*)d_ws;

    // d_ws is poisoned 0xAA before every launch — zero the accumulator (async, capture-safe)
    hipMemsetAsync(ws, 0, sizeof(double), stream);

    // Gaussian weights computed on host in double, passed via kernarg (SGPRs)
    GaussW gw;
    double g[TAPS], s = 0.0;
    for (int i = 0; i < TAPS; ++i) {
        double x = (double)(i - TAPS / 2);
        g[i] = exp(-(x * x) / (2.0 * 1.5 * 1.5));
        s += g[i];
    }
    for (int i = 0; i < TAPS; ++i) gw.w[i] = (float)(g[i] / s);

    // 2 x 16 x 48 = 1536 blocks; each block = 4 autonomous 64-col wave strips
    dim3 grid(IMG_W / (4 * STRIP), (IMG_H + CHUNK - 1) / CHUNK, NPLANES);
    ssim_main<<<grid, 256, 0, stream>>>(img1, img2, ws, gw);
    ssim_finalize<<<1, 1, 0, stream>>>(ws, out);
}

// Round 9
// 152.748 us; speedup vs baseline: 1.7887x; 1.7887x over previous
//
#include <hip/hip_runtime.h>
#include <math.h>

#define IMG_H 512
#define IMG_W 512
#define NPLANES 48            // 16 * 3
#define RAD 5
#define TAPS 11
#define CHUNK 33              // multiple of 11 -> static ring phase after unroll
#define STRIP 64              // columns per wave (one autonomous wave per strip)
#define SBUF 80               // 74 used (64 + 2*RAD), padded

typedef float v2f __attribute__((ext_vector_type(2)));

// Compiler-only fence: cross-lane LDS dependence (lane i reads what lane j
// wrote) is INVISIBLE to LLVM alias analysis — an early round failed
// correctness exactly this way (reads hoisted above writes). HW needs
// nothing: a wave has one PC and same-wave DS ops execute in-order at the
// LDS; the compiler auto-inserts minimal lgkmcnt before uses of read data.
// R15: the old RAW fence was a HARD s_waitcnt lgkmcnt(0) drain per row —
// replaced by this pure compile-order barrier (the drain was ~1/3 of the
// per-row critical path at 4 waves/SIMD).
#define WAVE_FENCE()  __asm__ __volatile__("" ::: "memory")

struct GaussW { float w[TAPS]; };

// Structure notes (evidence-driven). Ledger of proven failure triggers:
//  - R2/R7: any launch-bounds reg cap below the ~104 unified (VGPR+AGPR)
//    footprint spills the 55-float ring (WRITE_SIZE 48KB -> 200+MB,
//    70 -> 219+us). Keep (256,4) = 128-reg budget.
//  - R8/R9: FULL straight-line unroll of the row loop -> scheduler pipelines
//    loads across all rows -> pressure explosion -> spill. Keep the `for kk`
//    loop + 11-row `#pragma unroll` body EXACTLY.
//  - R14: float4 (a,b,a2,b2) staging doubled LDS read bytes/tap -> kernel
//    flipped to LDS-BW-bound (VALUBusy 20%, 188us). At 16 waves/CU this
//    kernel is near BOTH the VALU and LDS pipe limits: never trade VALU for
//    MORE LDS bytes. Staging stays (a,b) float2, squares computed in VALU.
//  - R10..R13: finalize-fold arc: fixed graph overhead ~83us regardless of
//    dispatch count, and the folded tail cost ~38us in-kernel. Fold dead.
//  - R3: per-row block barriers were lockstep. R5: one wave per 64-col
//    strip, no block barriers. R6: packed fp32 (v_pk_fma).
//  - R15 (this): body reorder. Old order staged row r and hconv'd it
//    IMMEDIATELY (write->read gap ~15 insts + lgkmcnt(0) drain per row).
//    New order: hconv(r) [staged last step] -> stage(r+1) -> issue loads
//    (r+2) -> vconv/ssim. Write->read distance ~100+ cyc, global prefetch
//    distance 2 rows (~440 cyc, covers L2 latency), no lgkm drain.
__global__ __launch_bounds__(256, 4)
void ssim_main(const float* __restrict__ img1, const float* __restrict__ img2,
               double* __restrict__ sum_ws, GaussW gw) {
    __shared__ float2 srow[4][SBUF];   // one private (a,b) row buffer per wave
    __shared__ float wsum[4];

    const int tid  = threadIdx.x;
    const int wid  = tid >> 6;         // wave id 0..3
    const int lane = tid & 63;
    const int c0   = blockIdx.x * (4 * STRIP) + wid * STRIP;  // strip base col
    const int y0   = blockIdx.y * CHUNK;
    const size_t pbase = (size_t)blockIdx.z * (IMG_H * IMG_W);
    const float* p1 = img1 + pbase;
    const float* p2 = img2 + pbase;
    float2* buf = srow[wid];

    // register ring, 11 rows deep:
    //   rab = (conv_h(a), conv_h(b))   packed
    //   rsq = (conv_h(a^2), conv_h(b^2)) packed
    //   rx  = conv_h(a*b)              scalar
    v2f rab[TAPS], rsq[TAPS];
    float rx[TAPS];

    // prefetch registers for the next row (main col + 10-col tail)
    float pa, pb, pta, ptb;

    auto load_regs = [&](int r) {
        pa = pb = pta = ptb = 0.f;
        if (r >= 0 && r < IMG_H) {     // wave-uniform
            const float* row1 = p1 + (size_t)r * IMG_W;
            const float* row2 = p2 + (size_t)r * IMG_W;
            int col = c0 - RAD + lane;              // buf idx = lane
            if (col >= 0 && col < IMG_W) { pa = row1[col]; pb = row2[col]; }
            if (lane < 2 * RAD) {                   // buf idx = 64+lane
                int c2 = c0 + STRIP - RAD + lane;   // cols c0+59..c0+68
                if (c2 < IMG_W) { pta = row1[c2]; ptb = row2[c2]; }
            }
        }
    };

    auto store_lds = [&]() {
        WAVE_FENCE();                  // WAR: don't sink writes above the
                                       // preceding hconv's reads (same buf)
        buf[lane] = make_float2(pa, pb);
        if (lane < 2 * RAD) buf[STRIP + lane] = make_float2(pta, ptb);
        WAVE_FENCE();                  // RAW order: next hconv's reads stay
                                       // below; HW in-order DS + auto lgkmcnt
                                       // on use — no drain needed
    };

    // packed horizontal conv: per tap 1 pk_mul + 1 mul + 2 pk_fma + 1 fma
    auto hconv = [&](int r, v2f& oab, v2f& osq, float& ox) {
        v2f aab = {0.f, 0.f}, asq = {0.f, 0.f};
        float ax = 0.f;
        if (r >= 0 && r < IMG_H) {     // wave-uniform: padded rows contribute zero
            #pragma unroll
            for (int d = 0; d < TAPS; ++d) {
                v2f v = *(const v2f*)&buf[lane + d];   // (a, b)
                float w = gw.w[d];
                v2f wv = {w, w};
                aab = __builtin_elementwise_fma(wv, v, aab);          // pk_fma
                v2f sq = v * v;                                       // pk_mul
                asq = __builtin_elementwise_fma(wv, sq, asq);         // pk_fma
                ax  = fmaf(w, v.x * v.y, ax);                         // mul+fma
            }
        }
        oab = aab; osq = osq = asq; ox = ax;
    };

    // ---- prologue: stage+hconv rows y0-5 .. y0+4 -> ring slots 0..9
    load_regs(y0 - RAD);
    #pragma unroll
    for (int k = 0; k < TAPS - 1; ++k) {
        const int r = y0 - RAD + k;
        store_lds();                   // stage row r (regs hold it)
        load_regs(r + 1);              // next row's loads in flight
        hconv(r, rab[k], rsq[k], rx[k]);
    }
    // prime the main-loop steady state: buffer must hold row y0+5 (hconv'd
    // at step 0), prefetch regs must hold row y0+6 in flight.
    store_lds();                       // stage row y0+5
    load_regs(y0 + RAD + 1);           // row y0+6 in flight

    const float C1v = 0.0001f;  // 0.01^2
    const float C2v = 0.0009f;  // 0.03^2
    float acc = 0.f;

    // ---- main: CHUNK output rows, unrolled by 11 so ring indices are static
    for (int kk = 0; kk < CHUNK; kk += TAPS) {
        #pragma unroll
        for (int j = 0; j < TAPS; ++j) {
            const int r = y0 + RAD + kk + j;   // row in buffer (staged last step)
            // 1) hconv row r from LDS (staged a full step ago -> no wait)
            hconv(r, rab[(j + 10) % TAPS], rsq[(j + 10) % TAPS], rx[(j + 10) % TAPS]);
            // 2) stage row r+1 (in prefetch regs; vmcnt wait auto on pa use)
            store_lds();
            // 3) issue loads for row r+2 -> 2-row prefetch distance
            load_regs(r + 2);
            // 4) vertical conv + SSIM for output row y (covers LDS latency
            //    of step 2's writes before next iteration's hconv reads)
            const int y = y0 + kk + j;
            if (y < IMG_H) {
                // packed vertical conv: per tap 2 pk_fma + 1 fma
                v2f mu = {0.f, 0.f}, s2 = {0.f, 0.f};
                float sx = 0.f;
                #pragma unroll
                for (int t = 0; t < TAPS; ++t) {
                    const int s = (j + t) % TAPS;  // static after unroll
                    float w = gw.w[t];
                    v2f wv = {w, w};
                    mu = __builtin_elementwise_fma(wv, rab[s], mu);
                    s2 = __builtin_elementwise_fma(wv, rsq[s], s2);
                    sx = fmaf(w, rx[s], sx);
                }
                float mu1 = mu.x, mu2 = mu.y;
                float mu1sq = mu1 * mu1, mu2sq = mu2 * mu2, mu12 = mu1 * mu2;
                float sg1 = s2.x - mu1sq, sg2 = s2.y - mu2sq, sg12 = sx - mu12;
                float num = (2.f * mu12 + C1v) * (2.f * sg12 + C2v);
                float den = (mu1sq + mu2sq + C1v) * (sg1 + sg2 + C2v);
                acc += num * __builtin_amdgcn_rcpf(den);
            }
        }
    }

    // wave (64-lane) shuffle reduce -> block partials -> one atomic per block
    #pragma unroll
    for (int off = 32; off > 0; off >>= 1) acc += __shfl_down(acc, off, 64);
    if (lane == 0) wsum[wid] = acc;
    __syncthreads();                   // only block barrier in the kernel
    if (tid == 0) {
        double s = (double)wsum[0] + (double)wsum[1] + (double)wsum[2] + (double)wsum[3];
        atomicAdd(sum_ws, s);
    }
}

__global__ void ssim_finalize(const double* __restrict__ sum_ws, float* __restrict__ out) {
    out[0] = (float)(sum_ws[0] * (1.0 / (double)(16.0 * 3.0 * 512.0 * 512.0)));
}

extern "C" void kernel_launch(void* const* d_in, const int* in_sizes, int n_in,
                              void* d_out, int out_size, void* d_ws, size_t ws_size,
                              hipStream_t stream) {
    const float* img1 = (const float*)d_in[0];
    const float* img2 = (const float*)d_in[1];
    float* out = (float*)d_out;
    double* ws = (double*)d_ws;

    // d_ws is poisoned 0xAA before every launch — zero the accumulator (async, capture-safe)
    hipMemsetAsync(ws, 0, sizeof(double), stream);

    // Gaussian weights computed on host in double, passed via kernarg (SGPRs)
    GaussW gw;
    double g[TAPS], s = 0.0;
    for (int i = 0; i < TAPS; ++i) {
        double x = (double)(i - TAPS / 2);
        g[i] = exp(-(x * x) / (2.0 * 1.5 * 1.5));
        s += g[i];
    }
    for (int i = 0; i < TAPS; ++i) gw.w[i] = (float)(g[i] / s);

    // 2 x 16 x 48 = 1536 blocks; each block = 4 autonomous 64-col wave strips
    dim3 grid(IMG_W / (4 * STRIP), (IMG_H + CHUNK - 1) / CHUNK, NPLANES);
    ssim_main<<<grid, 256, 0, stream>>>(img1, img2, ws, gw);
    ssim_finalize<<<1, 1, 0, stream>>>(ws, out);
}